// Round 2
// baseline (60.847 us; speedup 1.0000x reference)
//
#include <hip/hip_runtime.h>
#include <math.h>

// Problem constants (fixed by the reference):
//   B=8, N=256, D=16, K+1=4, REL=6, OUT=3
// Closed form (A = J - I fully connected; As input is IGNORED by the ref):
//   d<REL : Zagg = {0, T1-256*x1, 256*x2-T2-255*x1, 256*T3-65536*x3-255*x1}
//   d>=REL: Zagg = {x0, T1-x1, 254*T2+x2, 64771*T3-x3}
//   actions[b,i,o] = sum_{d,k} Zagg[d,k] * W[(d*4+k)*3+o], NaN->0
// where x_k = Xs[b,i,d,k], T_k[d] = sum_i Xs[b,i,d,k].
//
// NOTE (round 1 post-mortem): dur_us is dominated by the harness's 268 MB
// d_ws 0xAA poison (fillBufferAligned, ~42 us @ 80% HBM peak) inside the
// timed window. This kernel's real traffic is 0.5 MB read + 24 KB write.
// This round: latency-minimized variant (1024 thr/block) to bound the
// controllable share of dur_us.

constexpr int NN   = 256;
constexpr int DD   = 16;
constexpr int KP1  = 4;
constexpr int RELC = 6;
constexpr int LDS4 = 17;   // padded row stride in float4 units (16 data + 1 pad)
constexpr int NT   = 1024;

__global__ __launch_bounds__(NT)
void reynolds_kernel(const float* __restrict__ Xs,
                     const float* __restrict__ W,
                     float* __restrict__ out) {
    __shared__ float4 sX[NN * LDS4];     // 68 KiB, padded rows
    __shared__ float4 sPS[NT];           // 16 KiB per-thread partial sums
    __shared__ float  sT[DD * KP1];      // column sums T[d*4+k]
    __shared__ float  sW[DD * KP1 * 3];  // 768 B

    const int b = blockIdx.x;
    const int t = threadIdx.x;

    // --- Stage batch slice (4096 float4) into LDS, coalesced; accumulate
    //     per-thread partials. g = t + 1024*i -> float4 column c = t&15 is
    //     fixed per thread, i.e. a fixed (d=c, k=0..3) channel quad.
    const float4* src = (const float4*)(Xs + (size_t)b * NN * DD * KP1);
    const int c = t & 15;
    float4 a4 = make_float4(0.f, 0.f, 0.f, 0.f);
#pragma unroll
    for (int i = 0; i < 4; ++i) {
        const int g = t + i * NT;
        const float4 v = src[g];
        sX[(g >> 4) * LDS4 + c] = v;
        a4.x += v.x; a4.y += v.y; a4.z += v.z; a4.w += v.w;
    }
    sPS[t] = a4;
    if (t >= NT - DD * KP1 * 3) sW[t - (NT - DD * KP1 * 3)] = W[t - (NT - DD * KP1 * 3)];
    __syncthreads();

    // --- Reduce 1024 partials to T[d*4+k] (threads 0..63, one wave).
    if (t < 64) {
        const int d = t >> 2, k = t & 3;
        float s = 0.f;
#pragma unroll
        for (int j = 0; j < 64; ++j) {
            s += ((const float*)&sPS[d + 16 * j])[k];
        }
        sT[t] = s;
    }
    __syncthreads();

    // --- Per-row closed-form evaluation (threads 0..255 = rows).
    if (t < NN) {
        const float* xr = (const float*)&sX[t * LDS4];
        float acc0 = 0.f, acc1 = 0.f, acc2 = 0.f;
#pragma unroll
        for (int d = 0; d < DD; ++d) {
            const float x0 = xr[d * 4 + 0];
            const float x1 = xr[d * 4 + 1];
            const float x2 = xr[d * 4 + 2];
            const float x3 = xr[d * 4 + 3];
            const float T1 = sT[d * 4 + 1];
            const float T2 = sT[d * 4 + 2];
            const float T3 = sT[d * 4 + 3];
            float z0, z1, z2, z3;
            if (d < RELC) {   // compile-time branch (loop fully unrolled)
                z0 = 0.f;
                z1 = T1 - 256.f * x1;
                z2 = 256.f * x2 - T2 - 255.f * x1;
                z3 = 256.f * T3 - 65536.f * x3 - 255.f * x1;
            } else {
                z0 = x0;
                z1 = T1 - x1;
                z2 = 254.f * T2 + x2;
                z3 = 64771.f * T3 - x3;
            }
            const float* w = &sW[d * 12];
            acc0 += z0 * w[0] + z1 * w[3] + z2 * w[6] + z3 * w[9];
            acc1 += z0 * w[1] + z1 * w[4] + z2 * w[7] + z3 * w[10];
            acc2 += z0 * w[2] + z1 * w[5] + z2 * w[8] + z3 * w[11];
        }
        const size_t o = ((size_t)b * NN + t) * 3;
        out[o + 0] = isnan(acc0) ? 0.f : acc0;
        out[o + 1] = isnan(acc1) ? 0.f : acc1;
        out[o + 2] = isnan(acc2) ? 0.f : acc2;
    }
}

extern "C" void kernel_launch(void* const* d_in, const int* in_sizes, int n_in,
                              void* d_out, int out_size, void* d_ws, size_t ws_size,
                              hipStream_t stream) {
    // d_in[0] = As (IGNORED by the reference forward), d_in[1] = Xs, d_in[2] = W
    const float* Xs = (const float*)d_in[1];
    const float* W  = (const float*)d_in[2];
    float* out = (float*)d_out;
    reynolds_kernel<<<dim3(8), dim3(NT), 0, stream>>>(Xs, W, out);
}